// Round 11
// baseline (441.056 us; speedup 1.0000x reference)
//
#include <hip/hip_runtime.h>
#include <hip/hip_bf16.h>

#define DIM    16
#define BATCH  32
#define KL     4
#define NTS    512
#define NC     4
#define NPAR   16
#define DTF    (1.0f/512.0f)
#define BST    40     // bf16 operand row stride (ushort) for sP/sL
#define FST    20     // f32 tile row stride
#define TST    36     // paired-u32 T row stride (u32 units; 144 B, 16B-aligned)

using short8  = __attribute__((ext_vector_type(8))) short;
using short4v = __attribute__((ext_vector_type(4))) short;
using f32x4   = __attribute__((ext_vector_type(4))) float;

__device__ __forceinline__ float b2f(__hip_bfloat16 x) { return __bfloat162float(x); }

__device__ __forceinline__ float ldval(const void* p, int idx, bool isf32) {
  return isf32 ? ((const float*)p)[idx]
               : __bfloat162float(((const __hip_bfloat16*)p)[idx]);
}
__device__ __forceinline__ unsigned short f2bf(float x) {   // RNE (setup/L only)
  unsigned u = __float_as_uint(x);
  unsigned r = u + 0x7FFFu + ((u >> 16) & 1u);
  return (unsigned short)(r >> 16);
}
__device__ __forceinline__ float bf2f(unsigned short h) {
  return __uint_as_float(((unsigned)h) << 16);
}
// trunc-trunc hi/lo split (R10-verified): pair represents v to ~2^-16 rel
__device__ __forceinline__ void split2(float v, unsigned short& h, unsigned short& l) {
  unsigned u = __float_as_uint(v);
  h = (unsigned short)(u >> 16);
  float r = v - __uint_as_float(u & 0xFFFF0000u);
  l = (unsigned short)(__float_as_uint(r) >> 16);
}
__device__ __forceinline__ unsigned splitpack(float v) {    // u32 = hi | lo<<16
  unsigned short h, l;
  split2(v, h, l);
  return (unsigned)h | ((unsigned)l << 16);
}
__device__ __forceinline__ short8 ldfrag(const unsigned short* p) {
  return *(const short8*)p;
}
__device__ __forceinline__ short8 negbf8(short8 a) {
  union { short8 s; unsigned u[4]; } v; v.s = a;
  #pragma unroll
  for (int q = 0; q < 4; ++q) v.u[q] ^= 0x80008000u;
  return v.s;
}
__device__ __forceinline__ f32x4 mm3(short8 Ah, short8 Al, short8 Bh, short8 Bl, f32x4 acc) {
  acc = __builtin_amdgcn_mfma_f32_16x16x32_bf16(Ah, Bh, acc, 0, 0, 0);
  acc = __builtin_amdgcn_mfma_f32_16x16x32_bf16(Al, Bh, acc, 0, 0, 0);
  acc = __builtin_amdgcn_mfma_f32_16x16x32_bf16(Ah, Bl, acc, 0, 0, 0);
  return acc;
}
__device__ __forceinline__ void packfrag(const float* v, short8& hi, short8& lo) {
  union { short8 s; unsigned short e[8]; } H, L;
  #pragma unroll
  for (int q = 0; q < 8; ++q) split2(v[q], H.e[q], L.e[q]);
  hi = H.s; lo = L.s;
}
// load 8 paired u32 -> hi8/lo8 fragments via v_perm
__device__ __forceinline__ void ldfrag_paired(const unsigned* p, short8& hi, short8& lo) {
  uint4 wa = *(const uint4*)p;
  uint4 wb = *(const uint4*)(p + 4);
  union { short8 s; unsigned u[4]; } H, L;
  H.u[0] = __builtin_amdgcn_perm(wa.y, wa.x, 0x05040100u);
  H.u[1] = __builtin_amdgcn_perm(wa.w, wa.z, 0x05040100u);
  H.u[2] = __builtin_amdgcn_perm(wb.y, wb.x, 0x05040100u);
  H.u[3] = __builtin_amdgcn_perm(wb.w, wb.z, 0x05040100u);
  L.u[0] = __builtin_amdgcn_perm(wa.y, wa.x, 0x07060302u);
  L.u[1] = __builtin_amdgcn_perm(wa.w, wa.z, 0x07060302u);
  L.u[2] = __builtin_amdgcn_perm(wb.y, wb.x, 0x07060302u);
  L.u[3] = __builtin_amdgcn_perm(wb.w, wb.z, 0x07060302u);
  hi = H.s; lo = L.s;
}

__global__ __launch_bounds__(512, 1)
void lindblad_evolve(const void* __restrict__ g_params,
                     const void* __restrict__ g_H0re, const void* __restrict__ g_H0im,
                     const void* __restrict__ g_Hcre, const void* __restrict__ g_Hcim,
                     const void* __restrict__ g_Lre,  const void* __restrict__ g_Lim,
                     const void* __restrict__ g_r0re, const void* __restrict__ g_r0im,
                     float* __restrict__ g_out)
{
  __shared__ __align__(16) unsigned short sPh[16*BST], sPl[16*BST];         // rho^T' hi/lo
  __shared__ __align__(16) unsigned sTp[KL][16*TST];                        // T'_k paired u32
  __shared__ __align__(16) unsigned short sLh[KL][16*BST], sLl[KL][16*BST]; // L'_k
  __shared__ __align__(16) float sMr[16*FST], sMi[16*FST];                  // M normal layout only
  __shared__ __align__(16) float sU[NTS][NC];
  __shared__ __align__(16) float sPops[NTS*DIM];  // pops; first 2560 f32 = setup scratch
  __shared__ int sFlag;

  const int tid = threadIdx.x;
  const int b   = blockIdx.x;
  const int i   = tid >> 4;        // setup staging (tid<256)
  const int j   = tid & 15;
  const int wv  = tid >> 6;        // wave 0..7
  const int ln  = tid & 63;
  const int fm  = ln & 15;
  const int fq  = ln >> 4;
  const int row0 = fq * 4;
  const int fOff  = fm*BST + fq*8;
  const int fOffS = fm*BST + ((fq*8 + 16) & 31);

  // ---- input storage-dtype detection ----
  if (tid == 0) sFlag = 0;
  __syncthreads();
  if (tid < 256) {
    float v = b2f(((const __hip_bfloat16*)g_H0re)[tid]);
    if (!(fabsf(v) <= 1e10f)) atomicOr(&sFlag, 1);
  }
  __syncthreads();
  const bool isf32 = (sFlag != 0);

  // ---- B-spline control pulses (512 threads: one pass) ----
  {
    float kn[20];
    kn[0] = 0.f; kn[1] = 0.f; kn[2] = 0.f;
    #pragma unroll
    for (int q = 0; q < 14; ++q) kn[3 + q] = (float)q / 13.0f;
    kn[17] = 1.f; kn[18] = 1.f; kn[19] = 1.f;
    const float t = (float)tid * DTF;
    float B[19];
    #pragma unroll
    for (int q = 0; q < 19; ++q) B[q] = (kn[q] <= t && t < kn[q+1]) ? 1.f : 0.f;
    #pragma unroll
    for (int d = 1; d <= 3; ++d) {
      #pragma unroll
      for (int q = 0; q + d < 19; ++q) {
        float ld = kn[q+d]   - kn[q];
        float rd = kn[q+d+1] - kn[q+1];
        float lv = (ld > 0.f) ? (t - kn[q])     / ld * B[q]   : 0.f;
        float rv = (rd > 0.f) ? (kn[q+d+1] - t) / rd * B[q+1] : 0.f;
        B[q] = lv + rv;
      }
    }
    #pragma unroll
    for (int c = 0; c < NC; ++c) {
      float s = 0.f;
      #pragma unroll
      for (int q = 0; q < NPAR; ++q) s += B[q] * ldval(g_params, q*NC + c, isf32);
      sU[tid][c] = s;
    }
  }

  // ---- constants staging (threads 0..255, elementwise (i,j)) ----
  if (tid < 256) {
    float* scr = sPops;   // planes: 0=G0r 1=G0i 2+2c=Gc_r 3+2c=Gc_i
    const int ij = i*16 + j, ji = j*16 + i;
    float h0r = 0.5f * (ldval(g_H0re, ij, isf32) + ldval(g_H0re, ji, isf32));
    float h0i = 0.5f * (ldval(g_H0im, ij, isf32) - ldval(g_H0im, ji, isf32));
    float ldr = 0.f, ldi = 0.f;
    for (int k = 0; k < KL; ++k) {
      #pragma unroll
      for (int m = 0; m < DIM; ++m) {
        float ar = ldval(g_Lre, k*256 + m*16 + i, isf32), ai = ldval(g_Lim, k*256 + m*16 + i, isf32);
        float br = ldval(g_Lre, k*256 + m*16 + j, isf32), bi = ldval(g_Lim, k*256 + m*16 + j, isf32);
        ldr += ar*br + ai*bi;
        ldi += ar*bi - ai*br;
      }
    }
    scr[0*256 + ij] =  h0i - 0.5f*ldr;   // G0r
    scr[1*256 + ij] = -h0r - 0.5f*ldi;   // G0i
    #pragma unroll
    for (int c = 0; c < NC; ++c) {
      float hr = 0.5f * (ldval(g_Hcre, c*256 + ij, isf32) + ldval(g_Hcre, c*256 + ji, isf32));
      float hi = 0.5f * (ldval(g_Hcim, c*256 + ij, isf32) - ldval(g_Hcim, c*256 + ji, isf32));
      scr[(2 + 2*c)*256 + ij] =  hi;
      scr[(3 + 2*c)*256 + ij] = -hr;
    }
    // L': RNE hi/lo split (constant — keep tightest)
    #pragma unroll
    for (int k = 0; k < KL; ++k) {
      float lr = ldval(g_Lre, k*256 + ij, isf32);
      float li = ldval(g_Lim, k*256 + ij, isf32);
      unsigned short h;
      h = f2bf(lr); sLh[k][i*BST + j]      = h; sLl[k][i*BST + j]      = f2bf(lr - bf2f(h));
      h = f2bf(li); sLh[k][i*BST + 16 + j] = h; sLl[k][i*BST + 16 + j] = f2bf(li - bf2f(h));
    }
    // rho^T'(0)
    float r0 = ldval(g_r0re, b*256 + ij, isf32);
    float m0 = ldval(g_r0im, b*256 + ij, isf32);
    unsigned short h, l;
    split2(r0, h, l); sPh[j*BST + i]      = h; sPl[j*BST + i]      = l;
    split2(m0, h, l); sPh[j*BST + 16 + i] = h; sPl[j*BST + 16 + i] = l;
  }

  __syncthreads();   // scratch, sL, sP, sU visible

  // ---- per-wave loop-constant preloads ----
  // wv0: Mr + Jr + re-update (+G);  wv1: Mi + Ji + im-update (+G)
  // wv2: T0r+T0i; wv3: T1r+T1i; wv4: T2r; wv5: T3r; wv6: T2i; wv7: T3i
  short8 Ah, Al;                    // wv0/1: G frag (rebuilt per step); wv2-7: L'_k frag
  short8 JBh[KL], JBl[KL];          // wv0: straight; wv1: swap+neg
  float  G0v[8], Gcv[NC][8];        // wv0/1
  float  rm[4] = {0.f,0.f,0.f,0.f}; // wv0: rho_re master; wv1: rho_im master

  if (wv < 2) {
    const int comp = (fq < 2) ? 0 : 1;
    const int base = (fq & 1) * 8;
    const float* scr = sPops;
    {
      const float* s0 = &scr[comp*256 + fm*16 + base];
      f32x4 va = *(const f32x4*)s0, vb = *(const f32x4*)(s0 + 4);
      #pragma unroll
      for (int q = 0; q < 4; ++q) { G0v[q] = va[q]; G0v[4+q] = vb[q]; }
    }
    #pragma unroll
    for (int c = 0; c < NC; ++c) {
      const float* s0 = &scr[(2 + 2*c + comp)*256 + fm*16 + base];
      f32x4 va = *(const f32x4*)s0, vb = *(const f32x4*)(s0 + 4);
      #pragma unroll
      for (int q = 0; q < 4; ++q) { Gcv[c][q] = va[q]; Gcv[c][4+q] = vb[q]; }
    }
    f32x4 uv = *(const f32x4*)&sU[0][0];
    float gv[8];
    #pragma unroll
    for (int q = 0; q < 8; ++q)
      gv[q] = G0v[q] + uv[0]*Gcv[0][q] + uv[1]*Gcv[1][q] + uv[2]*Gcv[2][q] + uv[3]*Gcv[3][q];
    packfrag(gv, Ah, Al);
    if (wv == 0) {
      #pragma unroll
      for (int k = 0; k < KL; ++k) { JBh[k] = ldfrag(&sLh[k][fOff]); JBl[k] = ldfrag(&sLl[k][fOff]); }
      #pragma unroll
      for (int q = 0; q < 4; ++q) rm[q] = ldval(g_r0re, b*256 + (row0+q)*16 + fm, isf32);
    } else {
      #pragma unroll
      for (int k = 0; k < KL; ++k) {
        short8 h = ldfrag(&sLh[k][fOffS]);
        short8 l = ldfrag(&sLl[k][fOffS]);
        if (fq < 2) { h = negbf8(h); l = negbf8(l); }
        JBh[k] = h; JBl[k] = l;
      }
      #pragma unroll
      for (int q = 0; q < 4; ++q) rm[q] = ldval(g_r0im, b*256 + (row0+q)*16 + fm, isf32);
    }
  } else {
    // T-producer A operand: L_k with k = {wv2:0, wv3:1, wv4:2, wv5:3, wv6:2, wv7:3}
    const int k = (wv < 6) ? (wv - 2) : (wv - 4);
    Ah = ldfrag(&sLh[k][fOff]);
    Al = ldfrag(&sLl[k][fOff]);
  }

  // ---- main Euler loop: 2 barriers/step ----
  #pragma unroll 1
  for (int t = 0; t < NTS; ++t) {
    __syncthreads();   // B1: sP(t) visible

    f32x4 d1 = {0.f,0.f,0.f,0.f};   // wv0/1: own M tile (C-layout), kept in regs
    if (wv < 2) {
      short8 Bh, Bl;
      if (wv == 0) {
        Bh = ldfrag(&sPh[fOff]);  Bl = ldfrag(&sPl[fOff]);
        if (fq >= 2) { Bh = negbf8(Bh); Bl = negbf8(Bl); }
      } else {
        Bh = ldfrag(&sPh[fOffS]); Bl = ldfrag(&sPl[fOffS]);
      }
      d1 = mm3(Ah, Al, Bh, Bl, d1);
      float* Mn = (wv == 0) ? sMr : sMi;
      #pragma unroll
      for (int r = 0; r < 4; ++r) Mn[(row0 + r)*FST + fm] = d1[r];   // normal layout only
      // rebuild G'(t+1) fragment
      const int tn = (t + 1 < NTS) ? (t + 1) : t;
      f32x4 uv = *(const f32x4*)&sU[tn][0];
      float gv[8];
      #pragma unroll
      for (int q = 0; q < 8; ++q)
        gv[q] = G0v[q] + uv[0]*Gcv[0][q] + uv[1]*Gcv[1][q] + uv[2]*Gcv[2][q] + uv[3]*Gcv[3][q];
      packfrag(gv, Ah, Al);
    } else {
      const int k = (wv < 6) ? (wv - 2) : (wv - 4);
      if (wv < 4) {
        // both components
        short8 Brh = ldfrag(&sPh[fOff]),  Brl = ldfrag(&sPl[fOff]);
        if (fq >= 2) { Brh = negbf8(Brh); Brl = negbf8(Brl); }
        short8 Bih = ldfrag(&sPh[fOffS]), Bil = ldfrag(&sPl[fOffS]);
        f32x4 ar = {0.f,0.f,0.f,0.f}, ai = {0.f,0.f,0.f,0.f};
        ar = mm3(Ah, Al, Brh, Brl, ar);
        ai = mm3(Ah, Al, Bih, Bil, ai);
        #pragma unroll
        for (int r = 0; r < 4; ++r) {
          sTp[k][(row0 + r)*TST + fm]      = splitpack(ar[r]);
          sTp[k][(row0 + r)*TST + 16 + fm] = splitpack(ai[r]);
        }
      } else if (wv < 6) {
        // r component only
        short8 Bh = ldfrag(&sPh[fOff]), Bl = ldfrag(&sPl[fOff]);
        if (fq >= 2) { Bh = negbf8(Bh); Bl = negbf8(Bl); }
        f32x4 a = {0.f,0.f,0.f,0.f};
        a = mm3(Ah, Al, Bh, Bl, a);
        #pragma unroll
        for (int r = 0; r < 4; ++r) sTp[k][(row0 + r)*TST + fm] = splitpack(a[r]);
      } else {
        // i component only
        short8 Bh = ldfrag(&sPh[fOffS]), Bl = ldfrag(&sPl[fOffS]);
        f32x4 a = {0.f,0.f,0.f,0.f};
        a = mm3(Ah, Al, Bh, Bl, a);
        #pragma unroll
        for (int r = 0; r < 4; ++r) sTp[k][(row0 + r)*TST + 16 + fm] = splitpack(a[r]);
      }
    }

    __syncthreads();   // B2: sT, sM visible

    if (wv < 2) {
      // ---- J + update (wv0: re, wv1: im) ----
      short8 T0h, T0l, T1h, T1l, T2h, T2l, T3h, T3l;
      ldfrag_paired(&sTp[0][fm*TST + fq*8], T0h, T0l);
      ldfrag_paired(&sTp[1][fm*TST + fq*8], T1h, T1l);
      ldfrag_paired(&sTp[2][fm*TST + fq*8], T2h, T2l);
      ldfrag_paired(&sTp[3][fm*TST + fq*8], T3h, T3l);
      f32x4 a0 = {0.f,0.f,0.f,0.f}, a1 = {0.f,0.f,0.f,0.f},
            a2 = {0.f,0.f,0.f,0.f}, a3 = {0.f,0.f,0.f,0.f};
      a0 = mm3(T0h, T0l, JBh[0], JBl[0], a0);
      a1 = mm3(T1h, T1l, JBh[1], JBl[1], a1);
      a2 = mm3(T2h, T2l, JBh[2], JBl[2], a2);
      a3 = mm3(T3h, T3l, JBh[3], JBl[3], a3);
      const float* Mn = (wv == 0) ? sMr : sMi;
      f32x4 d2 = *(const f32x4*)&Mn[fm*FST + row0];   // M[fm][row0+q] (transpose term)
      union { short4v s; unsigned short e[4]; } HH, LL;
      if (wv == 0) {
        #pragma unroll
        for (int q = 0; q < 4; ++q) {
          rm[q] += DTF * (d1[q] + d2[q] + ((a0[q] + a1[q]) + (a2[q] + a3[q])));
          split2(rm[q], HH.e[q], LL.e[q]);
        }
        *(short4v*)&sPh[fm*BST + row0] = HH.s;
        *(short4v*)&sPl[fm*BST + row0] = LL.s;
        if ((unsigned)(fm - row0) < 4u) sPops[t*DIM + fm] = rm[fm - row0];
      } else {
        #pragma unroll
        for (int q = 0; q < 4; ++q) {
          rm[q] += DTF * (d1[q] - d2[q] + ((a0[q] + a1[q]) + (a2[q] + a3[q])));
          split2(rm[q], HH.e[q], LL.e[q]);
        }
        *(short4v*)&sPh[fm*BST + 16 + row0] = HH.s;
        *(short4v*)&sPl[fm*BST + 16 + row0] = LL.s;
      }
    }
    // wv2-7: idle in phase 2
  }

  // ---- final coalesced pops flush ----
  __syncthreads();
  #pragma unroll
  for (int s = 0; s < NTS*DIM/512; ++s) {
    int idx = s*512 + tid;                      // idx = t*16 + d
    g_out[(idx >> 4)*(BATCH*DIM) + b*DIM + (idx & 15)] = sPops[idx];
  }
}

extern "C" void kernel_launch(void* const* d_in, const int* in_sizes, int n_in,
                              void* d_out, int out_size, void* d_ws, size_t ws_size,
                              hipStream_t stream) {
  (void)out_size; (void)d_ws; (void)ws_size;
  const void *P, *H0r, *H0i, *Hcr, *Hci, *Lr, *Li, *R0r, *R0i;
  int idx64 = -1;
  for (int q = 0; q < n_in; ++q) if (in_sizes[q] == 64) idx64 = q;
  if (idx64 == 6) {   // alphabetical fallback
    H0i = d_in[0]; H0r = d_in[1];
    Hci = d_in[2]; Hcr = d_in[3];
    Li  = d_in[4]; Lr  = d_in[5];
    P   = d_in[6];
    R0i = d_in[7]; R0r = d_in[8];
  } else {            // documented setup_inputs() dict order (R4-verified)
    P   = d_in[0];
    H0r = d_in[1]; H0i = d_in[2];
    Hcr = d_in[3]; Hci = d_in[4];
    Lr  = d_in[5]; Li  = d_in[6];
    R0r = d_in[7]; R0i = d_in[8];
  }
  lindblad_evolve<<<dim3(BATCH), dim3(512), 0, stream>>>(
      P, H0r, H0i, Hcr, Hci, Lr, Li, R0r, R0i, (float*)d_out);
}